// Round 6
// baseline (1290.708 us; speedup 1.0000x reference)
//
#include <hip/hip_runtime.h>
#include <hip/hip_bf16.h>
#include <stdint.h>

// ---- problem dims (fixed by setup_inputs) ----
#define DIM   4096
#define HID   11008
#define MTOK  4096              // B*S = 2*2048
#define NELW  (HID * DIM)       // 45,088,768 elements per weight matrix

typedef __bf16 bf16x8 __attribute__((ext_vector_type(8)));
typedef float  f32x16 __attribute__((ext_vector_type(16)));
using gptr_t = const __attribute__((address_space(1))) void*;
using lptr_t = __attribute__((address_space(3))) void*;

__device__ __forceinline__ float bf2f(unsigned short u) {
    unsigned int t = ((unsigned int)u) << 16;
    float f; __builtin_memcpy(&f, &t, 4); return f;
}
__device__ __forceinline__ unsigned short f2bf(float f) {   // RNE
    unsigned int x; __builtin_memcpy(&x, &f, 4);
    x += 0x7fffu + ((x >> 16) & 1u);
    return (unsigned short)(x >> 16);
}

__device__ __constant__ float NF4_TAB[16] = {
    -1.0f, -0.6961928009986877f, -0.5250730514526367f, -0.39491748809814453f,
    -0.28444138169288635f, -0.18477343022823334f, -0.09105003625154495f, 0.0f,
    0.07958029955625534f, 0.16093020141124725f, 0.24611230194568634f,
    0.33791524171829224f, 0.44070982933044434f, 0.5626170039176941f,
    0.6989939212799072f, 1.0f};

// dequant 8 codes at element offset `base` (table via wave shfl from lanes 0-15)
__device__ __forceinline__ void dq8(const int* codes, const float* absmax,
                                    unsigned short* out, long base, float tv)
{
    int4 c0 = *(const int4*)(codes + base);
    int4 c1 = *(const int4*)(codes + base + 4);
    float s = absmax[base >> 6];
    union { uint4 q; unsigned short u[8]; } o;
    o.u[0] = f2bf(__shfl(tv, c0.x) * s);
    o.u[1] = f2bf(__shfl(tv, c0.y) * s);
    o.u[2] = f2bf(__shfl(tv, c0.z) * s);
    o.u[3] = f2bf(__shfl(tv, c0.w) * s);
    o.u[4] = f2bf(__shfl(tv, c1.x) * s);
    o.u[5] = f2bf(__shfl(tv, c1.y) * s);
    o.u[6] = f2bf(__shfl(tv, c1.z) * s);
    o.u[7] = f2bf(__shfl(tv, c1.w) * s);
    *(uint4*)(out + base) = o.q;
}

// preamble: blocks [0, 22016) dequant W1; blocks [22016, 30208) cast x->bf16
#define W1BLK 22016
#define PREBLK (W1BLK + (MTOK * DIM) / 2048)
__global__ __launch_bounds__(256) void pre_k(
    const int* __restrict__ w1c, const float* __restrict__ w1a,
    unsigned short* __restrict__ W1,
    const float* __restrict__ x, unsigned short* __restrict__ Xb)
{
    float tv = NF4_TAB[threadIdx.x & 15];
    if ((int)blockIdx.x < W1BLK) {
        long base = ((long)blockIdx.x * 256 + threadIdx.x) * 8;
        dq8(w1c, w1a, W1, base, tv);
    } else {
        long base = ((long)(blockIdx.x - W1BLK) * 256 + threadIdx.x) * 8;
        float4 a = *(const float4*)(x + base);
        float4 b = *(const float4*)(x + base + 4);
        union { uint4 q; unsigned short u[8]; } o;
        o.u[0] = f2bf(a.x); o.u[1] = f2bf(a.y); o.u[2] = f2bf(a.z); o.u[3] = f2bf(a.w);
        o.u[4] = f2bf(b.x); o.u[5] = f2bf(b.y); o.u[6] = f2bf(b.z); o.u[7] = f2bf(b.w);
        *(uint4*)(Xb + base) = o.q;
    }
}

// ============================================================================
// 256x256-tile 4-phase/K-tile GEMM, 32x32x16 MFMA (R6).
// C[m,n] = sum_k A[m,k]*B[n,k]; A:[M,K] bf16, B:[N,K] bf16 row-major.
// 512 thr = 8 waves (2M x 4N); BK=64; LDS 128 KiB (2buf x {A,B} x 2half).
//
// vmcnt LEDGER (r3/r4-verified; 2 loads per STAGE) -- UNCHANGED by the MFMA
// switch: prologue 12 issues, vmcnt(4)+BAR publishes tile0; iter t: ph1
// B0[t+1], ph2 B1[t+1], ph3 A0[t+2] + vmcnt(6) publishes A[t+1], ph4
// A1[t+2] + vmcnt(4) publishes B[t+1].  In-flight never <4.
//
// 32x32x16 layouts: A/B frag: row(col)=lane&31, k=(lane>>5)*8+j (4 VGPR);
// C/D: col=lane&31, row=(reg&3)+8*(reg>>2)+4*(lane>>5)  [m74/m101].
// Per wave 128x64 out = 4x2 tiles of 32x32; per phase 8 MFMA (one mtile-pair
// x one ntile x 4 k-slices).
//
// Blocks >= ngemm run grid-stride NF4 dequant (dqc/dqa->dqo) instead -- tail
// fill; consumer is the NEXT dispatch (dispatch boundary = fence).
// MODE: 0 = f32 out, 1 = bf16 out, 2 = bf16 fused h=silu(Cout)*acc in-place.
// ============================================================================
template<int MODE>
__global__ __launch_bounds__(512, 2) void gemm256_k(
    const unsigned short* __restrict__ A, const unsigned short* __restrict__ B,
    void* __restrict__ Cout, int M, int N, int K, int ngemm,
    const int* __restrict__ dqc, const float* __restrict__ dqa,
    unsigned short* __restrict__ dqo)
{
    __shared__ __align__(16) unsigned short lds[2][2][2][128 * 64];

    const int tid = threadIdx.x;
    const int lane = tid & 63;

    if ((int)blockIdx.x >= ngemm) {          // ---- tail: grid-stride dequant
        if (!dqo) return;
        const int b = (int)blockIdx.x - ngemm;
        const int ndq = (int)gridDim.x - ngemm;
        const long stride = (long)ndq * 512 * 8;
        float tv = NF4_TAB[lane & 15];
        for (long base = ((long)b * 512 + tid) * 8; base < (long)NELW; base += stride)
            dq8(dqc, dqa, dqo, base, tv);
        return;
    }

    const int w = tid >> 6;
    const int wm = w >> 2, wn = w & 3;           // 2M x 4N wave grid
    const int l31 = lane & 31, l5 = lane >> 5;
    const int key = lane & 7;                    // read-side swizzle key (=row&7)

    const int nbm = M >> 8, nbn = N >> 8;
    const int cpx = (nbm * nbn) >> 3;            // ngemm%8==0 -> bijective
    int swz = ((int)blockIdx.x & 7) * cpx + ((int)blockIdx.x >> 3);
    const int bm = swz % nbm, bn = swz / nbm;    // bm fastest: B-panel reuse

    const long ldK = K;
    const int srow = tid >> 3;                   // 0..63 staging row
    const int scol = ((tid & 7) ^ (srow & 7)) * 8;   // pre-swizzled source col
    const unsigned short* gA = A + ((long)(bm * 256 + srow)) * ldK + scol;
    const unsigned short* gB = B + ((long)(bn * 256 + srow)) * ldK + scol;

    f32x16 acc[4][2];
    #pragma unroll
    for (int m = 0; m < 4; ++m)
        #pragma unroll
        for (int n = 0; n < 2; ++n)
            #pragma unroll
            for (int r = 0; r < 16; ++r) acc[m][n][r] = 0.f;

    bf16x8 aLo[2][4], aHi[2][4], bLo[4], bHi[4];

    // stage half-tile h (0=A rows0-127, 1=A rows128-255, 2=B0, 3=B1) of K-tile
    auto STAGE = [&](int kt, int h, int b) {
        const unsigned short* src = ((h >> 1) ? gB : gA)
            + (long)((h & 1) * 128) * ldK + (long)kt * 64;
        char* dst = (char*)&lds[b][h >> 1][h & 1][0] + w * 1024;
        __builtin_amdgcn_global_load_lds((gptr_t)src, (lptr_t)dst, 16, 0, 0);
        __builtin_amdgcn_global_load_lds((gptr_t)(src + (long)64 * ldK),
                                         (lptr_t)(dst + 8192), 16, 0, 0);
    };
    // A frags: which=0 -> mtiles {0,1} (rows 0-63 of wave half), 1 -> {2,3}
    auto LDA32 = [&](bf16x8 (&fr)[2][4], int which, int b) {
        const unsigned short* base = &lds[b][0][wm][0];
        #pragma unroll
        for (int mt = 0; mt < 2; ++mt)
            #pragma unroll
            for (int ks = 0; ks < 4; ++ks) {
                const int row = which * 64 + mt * 32 + l31;
                fr[mt][ks] = *(const bf16x8*)(base + row * 64
                                              + (((ks * 2 + l5) ^ key) * 8));
            }
    };
    // B frags: which = ntile 0/1 (cols 0-31 / 32-63 of wave's 64-col strip)
    auto LDB32 = [&](bf16x8 (&fr)[4], int which, int b) {
        const unsigned short* base = &lds[b][1][wn >> 1][0];
        #pragma unroll
        for (int ks = 0; ks < 4; ++ks) {
            const int row = (wn & 1) * 64 + which * 32 + l31;
            fr[ks] = *(const bf16x8*)(base + row * 64
                                      + (((ks * 2 + l5) ^ key) * 8));
        }
    };
    auto MMA32 = [&](bf16x8 (&fa)[2][4], bf16x8 (&fb)[4], int mo, int no) {
        __builtin_amdgcn_s_setprio(1);
        #pragma unroll
        for (int mt = 0; mt < 2; ++mt)
            #pragma unroll
            for (int ks = 0; ks < 4; ++ks)
                acc[mo + mt][no] = __builtin_amdgcn_mfma_f32_32x32x16_bf16(
                    fa[mt][ks], fb[ks], acc[mo + mt][no], 0, 0, 0);
        __builtin_amdgcn_s_setprio(0);
    };
    #define BAR() do { __builtin_amdgcn_s_barrier(); \
                       __builtin_amdgcn_sched_barrier(0xF); } while (0)

    const int NT = K >> 6;
    // ---- prologue: tile0 fully + A-halves of tile1; publish tile0, THEN read
    STAGE(0, 0, 0); STAGE(0, 1, 0); STAGE(0, 2, 0); STAGE(0, 3, 0);
    STAGE(1, 0, 1); STAGE(1, 1, 1);
    asm volatile("s_waitcnt vmcnt(4)" ::: "memory");   // own tile0 loads landed
    BAR();                                             // ...and everyone else's
    LDA32(aLo, 0, 0);

    int cur = 0;
    for (int t = 0; t < NT - 1; ++t) {
        const int nb = cur ^ 1;
        const int tA = (t + 2 < NT) ? t + 2 : NT - 1;  // clamped: dupes land dead
        // ph1
        STAGE(t + 1, 2, nb);
        LDB32(bLo, 0, cur);
        BAR();
        MMA32(aLo, bLo, 0, 0);
        BAR();
        // ph2
        STAGE(t + 1, 3, nb);
        LDA32(aHi, 1, cur);
        BAR();
        MMA32(aHi, bLo, 2, 0);
        BAR();
        // ph3 (+ publish A[t+1])
        STAGE(tA, 0, cur);
        LDB32(bHi, 1, cur);
        BAR();
        MMA32(aLo, bHi, 0, 1);
        asm volatile("s_waitcnt vmcnt(6)" ::: "memory");
        BAR();
        // ph4 (+ publish B[t+1])
        STAGE(tA, 1, cur);
        LDA32(aLo, 0, nb);
        BAR();
        MMA32(aHi, bHi, 2, 1);
        asm volatile("s_waitcnt vmcnt(4)" ::: "memory");
        BAR();
        cur = nb;
    }
    // ---- epilogue: last tile, fully published ----
    LDB32(bLo, 0, cur);
    MMA32(aLo, bLo, 0, 0);
    LDA32(aHi, 1, cur);
    MMA32(aHi, bLo, 2, 0);
    LDB32(bHi, 1, cur);
    MMA32(aLo, bHi, 0, 1);
    MMA32(aHi, bHi, 2, 1);
    #undef BAR

    // ---- C write.  32x32 C/D: col=lane&31, row=(reg&3)+8*(reg>>2)+4*(lane>>5)
    const int grow0 = bm * 256 + wm * 128 + l5 * 4;
    const int gcol0 = bn * 256 + wn * 64 + l31;
    #pragma unroll
    for (int mt = 0; mt < 4; ++mt)
        #pragma unroll
        for (int nt = 0; nt < 2; ++nt)
            #pragma unroll
            for (int r = 0; r < 16; ++r) {
                const int row = grow0 + mt * 32 + (r & 3) + 8 * (r >> 2);
                const long idx = (long)row * N + gcol0 + nt * 32;
                if (MODE == 0) {
                    ((float*)Cout)[idx] = acc[mt][nt][r];
                } else if (MODE == 1) {
                    ((unsigned short*)Cout)[idx] = f2bf(acc[mt][nt][r]);
                } else {
                    unsigned short* C = (unsigned short*)Cout;
                    float h1v = bf2f(C[idx]);
                    float g = h1v / (1.0f + __expf(-h1v));
                    C[idx] = f2bf(g * acc[mt][nt][r]);
                }
            }
}

// ---- workspace layout (bytes) ----
//  [0)          W1 bf16 (90,177,536)
//  [90177536)   W3 bf16 (90,177,536)  -- later reused for W2
//  [180355072)  x  bf16 (33,554,432)
//  [213909504)  h1 bf16 (90,177,536)  -- fused swiglu written in-place by GEMM2
//  total 304,087,040
#define WS_NEEDED 304087040UL
#define DQBLK 512     // tail dequant blocks appended to GEMM1/GEMM2 dispatches

extern "C" void kernel_launch(void* const* d_in, const int* in_sizes, int n_in,
                              void* d_out, int out_size, void* d_ws, size_t ws_size,
                              hipStream_t stream) {
    const float* x   = (const float*)d_in[0];
    const int*   w1c = (const int*)d_in[1];
    const float* w1a = (const float*)d_in[2];
    const int*   w2c = (const int*)d_in[3];
    const float* w2a = (const float*)d_in[4];
    const int*   w3c = (const int*)d_in[5];
    const float* w3a = (const float*)d_in[6];

    if (ws_size < WS_NEEDED) return;   // fail loudly via validation

    char* ws = (char*)d_ws;
    unsigned short* W1 = (unsigned short*)(ws);
    unsigned short* W3 = (unsigned short*)(ws + 90177536);   // also W2 later
    unsigned short* Xb = (unsigned short*)(ws + 180355072);
    unsigned short* H1 = (unsigned short*)(ws + 213909504);

    // preamble: W1 dequant + x cast (one dispatch)
    pre_k<<<PREBLK, 256, 0, stream>>>(w1c, w1a, W1, x, Xb);

    const int g12 = (MTOK / 256) * (HID / 256);   // 688
    const int g3  = (MTOK / 256) * (DIM / 256);   // 256

    // h1 = x @ W1^T; tail blocks dequant W3 -> consumed by NEXT dispatch
    gemm256_k<1><<<g12 + DQBLK, 512, 0, stream>>>(Xb, W1, H1, MTOK, HID, DIM,
                                                  g12, w3c, w3a, W3);
    // h = silu(h1) * (x @ W3^T) in-place; tail blocks dequant W2 into W1's buf
    // (GEMM1 retired at dispatch boundary; this dispatch reads only Xb/W3/H1)
    gemm256_k<2><<<g12 + DQBLK, 512, 0, stream>>>(Xb, W3, H1, MTOK, HID, DIM,
                                                  g12, w2c, w2a, W1);
    // out = h @ W2^T (W2 lives in W1's buffer), fp32 output
    gemm256_k<0><<<g3, 512, 0, stream>>>(H1, W1, (float*)d_out, MTOK, DIM, HID,
                                         g3, nullptr, nullptr, nullptr);
}

// Round 7
// 1134.654 us; speedup vs baseline: 1.1375x; 1.1375x over previous
//
#include <hip/hip_runtime.h>
#include <hip/hip_bf16.h>
#include <stdint.h>

// ---- problem dims (fixed by setup_inputs) ----
#define DIM   4096
#define HID   11008
#define MTOK  4096              // B*S = 2*2048
#define NELW  (HID * DIM)       // 45,088,768 elements per weight matrix

typedef __bf16 bf16x8 __attribute__((ext_vector_type(8)));
typedef float  f32x4  __attribute__((ext_vector_type(4)));
using gptr_t = const __attribute__((address_space(1))) void*;
using lptr_t = __attribute__((address_space(3))) void*;

__device__ __forceinline__ float bf2f(unsigned short u) {
    unsigned int t = ((unsigned int)u) << 16;
    float f; __builtin_memcpy(&f, &t, 4); return f;
}
__device__ __forceinline__ unsigned short f2bf(float f) {   // RNE
    unsigned int x; __builtin_memcpy(&x, &f, 4);
    x += 0x7fffu + ((x >> 16) & 1u);
    return (unsigned short)(x >> 16);
}

__device__ __constant__ float NF4_TAB[16] = {
    -1.0f, -0.6961928009986877f, -0.5250730514526367f, -0.39491748809814453f,
    -0.28444138169288635f, -0.18477343022823334f, -0.09105003625154495f, 0.0f,
    0.07958029955625534f, 0.16093020141124725f, 0.24611230194568634f,
    0.33791524171829224f, 0.44070982933044434f, 0.5626170039176941f,
    0.6989939212799072f, 1.0f};

// dequant 8 codes at element offset `base` (table via wave shfl from lanes 0-15)
__device__ __forceinline__ void dq8(const int* codes, const float* absmax,
                                    unsigned short* out, long base, float tv)
{
    int4 c0 = *(const int4*)(codes + base);
    int4 c1 = *(const int4*)(codes + base + 4);
    float s = absmax[base >> 6];
    union { uint4 q; unsigned short u[8]; } o;
    o.u[0] = f2bf(__shfl(tv, c0.x) * s);
    o.u[1] = f2bf(__shfl(tv, c0.y) * s);
    o.u[2] = f2bf(__shfl(tv, c0.z) * s);
    o.u[3] = f2bf(__shfl(tv, c0.w) * s);
    o.u[4] = f2bf(__shfl(tv, c1.x) * s);
    o.u[5] = f2bf(__shfl(tv, c1.y) * s);
    o.u[6] = f2bf(__shfl(tv, c1.z) * s);
    o.u[7] = f2bf(__shfl(tv, c1.w) * s);
    *(uint4*)(out + base) = o.q;
}

// preamble: blocks [0, 22016) dequant W1; blocks [22016, 30208) cast x->bf16
#define W1BLK 22016
#define PREBLK (W1BLK + (MTOK * DIM) / 2048)
__global__ __launch_bounds__(256) void pre_k(
    const int* __restrict__ w1c, const float* __restrict__ w1a,
    unsigned short* __restrict__ W1,
    const float* __restrict__ x, unsigned short* __restrict__ Xb)
{
    float tv = NF4_TAB[threadIdx.x & 15];
    if ((int)blockIdx.x < W1BLK) {
        long base = ((long)blockIdx.x * 256 + threadIdx.x) * 8;
        dq8(w1c, w1a, W1, base, tv);
    } else {
        long base = ((long)(blockIdx.x - W1BLK) * 256 + threadIdx.x) * 8;
        float4 a = *(const float4*)(x + base);
        float4 b = *(const float4*)(x + base + 4);
        union { uint4 q; unsigned short u[8]; } o;
        o.u[0] = f2bf(a.x); o.u[1] = f2bf(a.y); o.u[2] = f2bf(a.z); o.u[3] = f2bf(a.w);
        o.u[4] = f2bf(b.x); o.u[5] = f2bf(b.y); o.u[6] = f2bf(b.z); o.u[7] = f2bf(b.w);
        *(uint4*)(Xb + base) = o.q;
    }
}

// ============================================================================
// 256x256-tile 4-phase/K-tile GEMM — R5 core verbatim (16x16x32 MFMA, measured
// 0 bank conflicts), + grid-stride dequant tail blocks (R6 fusion, kept).
// C[m,n] = sum_k A[m,k]*B[n,k]; A:[M,K] bf16, B:[N,K] bf16 row-major.
// 512 thr = 8 waves (2M x 4N); BK=64; LDS 128 KiB (2buf x {A,B} x 2half).
//
// vmcnt LEDGER (r3/r4-verified; 2 loads per STAGE): prologue 12 issues,
// vmcnt(4)+BAR publishes tile0; iter t: ph1 B0[t+1], ph2 B1[t+1], ph3
// A0[t+2] + vmcnt(6) publishes A[t+1], ph4 A1[t+2] + vmcnt(4) publishes
// B[t+1].  In-flight never <4 (T4).  Every ds_read is lgkmcnt-drained by its
// consuming MFMA before the barrier preceding the overwriting STAGE.
//
// R6 lesson (reverted): 32x32x16 MFMA caused ~4 cyc/read bank conflict
// (3.4e7/dispatch) + 4-deep dependent acc chains -> −15%.  16x16 stays.
//
// Blocks >= ngemm run grid-stride NF4 dequant (dqc/dqa->dqo) -- tail fill;
// consumer is the NEXT dispatch (dispatch boundary = fence).
// MODE: 0 = f32 out, 1 = bf16 out, 2 = bf16 fused h=silu(Cout)*acc in-place.
// ============================================================================
template<int MODE>
__global__ __launch_bounds__(512, 2) void gemm256_k(
    const unsigned short* __restrict__ A, const unsigned short* __restrict__ B,
    void* __restrict__ Cout, int M, int N, int K, int ngemm,
    const int* __restrict__ dqc, const float* __restrict__ dqa,
    unsigned short* __restrict__ dqo)
{
    __shared__ __align__(16) unsigned short lds[2][2][2][128 * 64];

    const int tid = threadIdx.x;
    const int lane = tid & 63;

    if ((int)blockIdx.x >= ngemm) {          // ---- tail: grid-stride dequant
        if (!dqo) return;
        const int b = (int)blockIdx.x - ngemm;
        const int ndq = (int)gridDim.x - ngemm;
        const long stride = (long)ndq * 512 * 8;
        float tv = NF4_TAB[lane & 15];
        for (long base = ((long)b * 512 + tid) * 8; base < (long)NELW; base += stride)
            dq8(dqc, dqa, dqo, base, tv);
        return;
    }

    const int w = tid >> 6;
    const int wm = w >> 2, wn = w & 3;           // 2M x 4N wave grid
    const int lrow = lane & 15, hi = lane >> 4;
    const int key = lrow & 7;                    // read-side swizzle key

    const int nbm = M >> 8, nbn = N >> 8;
    const int cpx = (nbm * nbn) >> 3;            // ngemm%8==0 -> bijective
    int swz = ((int)blockIdx.x & 7) * cpx + ((int)blockIdx.x >> 3);
    const int bm = swz % nbm, bn = swz / nbm;    // bm fastest: B-panel reuse

    const long ldK = K;
    const int srow = tid >> 3;                   // 0..63 staging row
    const int scol = ((tid & 7) ^ (srow & 7)) * 8;   // pre-swizzled source col
    const unsigned short* gA = A + ((long)(bm * 256 + srow)) * ldK + scol;
    const unsigned short* gB = B + ((long)(bn * 256 + srow)) * ldK + scol;

    f32x4 acc[8][4];
    #pragma unroll
    for (int m = 0; m < 8; ++m)
        #pragma unroll
        for (int n = 0; n < 4; ++n) acc[m][n] = f32x4{0.f, 0.f, 0.f, 0.f};

    bf16x8 a0[4][2], a1[4][2], b0[2][2], b1[2][2];

    // stage half-tile h (0=A rows0-127, 1=A rows128-255, 2=B0, 3=B1) of K-tile
    auto STAGE = [&](int kt, int h, int b) {
        const unsigned short* src = ((h >> 1) ? gB : gA)
            + (long)((h & 1) * 128) * ldK + (long)kt * 64;
        char* dst = (char*)&lds[b][h >> 1][h & 1][0] + w * 1024;
        __builtin_amdgcn_global_load_lds((gptr_t)src, (lptr_t)dst, 16, 0, 0);
        __builtin_amdgcn_global_load_lds((gptr_t)(src + (long)64 * ldK),
                                         (lptr_t)(dst + 8192), 16, 0, 0);
    };
    // lane's A fragments: which=0 -> rows 0-63 of wave's half, 1 -> rows 64-127
    auto LDA = [&](bf16x8 (&fr)[4][2], int which, int b) {
        const unsigned short* base = &lds[b][0][wm][0];
        #pragma unroll
        for (int m = 0; m < 4; ++m)
            #pragma unroll
            for (int ks = 0; ks < 2; ++ks)
                fr[m][ks] = *(const bf16x8*)(base + (which * 64 + m * 16 + lrow) * 64
                                             + (((ks * 4 + hi) ^ key) * 8));
    };
    // lane's B fragments: which=0 -> n0..1, 1 -> n2..3
    auto LDB = [&](bf16x8 (&fr)[2][2], int which, int b) {
        const unsigned short* base = &lds[b][1][wn >> 1][0];
        #pragma unroll
        for (int n = 0; n < 2; ++n)
            #pragma unroll
            for (int ks = 0; ks < 2; ++ks)
                fr[n][ks] = *(const bf16x8*)(base + ((wn & 1) * 64 + (which * 2 + n) * 16 + lrow) * 64
                                             + (((ks * 4 + hi) ^ key) * 8));
    };
    auto MMA = [&](bf16x8 (&fa)[4][2], bf16x8 (&fb)[2][2], int mo, int no) {
        __builtin_amdgcn_s_setprio(1);
        #pragma unroll
        for (int m = 0; m < 4; ++m)
            #pragma unroll
            for (int n = 0; n < 2; ++n)
                #pragma unroll
                for (int ks = 0; ks < 2; ++ks)
                    acc[mo + m][no + n] = __builtin_amdgcn_mfma_f32_16x16x32_bf16(
                        fa[m][ks], fb[n][ks], acc[mo + m][no + n], 0, 0, 0);
        __builtin_amdgcn_s_setprio(0);
    };
    // s_barrier + sched fence for memory classes (ALU/VALU/SALU/MFMA may cross)
    #define BAR() do { __builtin_amdgcn_s_barrier(); \
                       __builtin_amdgcn_sched_barrier(0xF); } while (0)

    const int NT = K >> 6;
    // ---- prologue: tile0 fully + A-halves of tile1; publish tile0, THEN read
    STAGE(0, 0, 0); STAGE(0, 1, 0); STAGE(0, 2, 0); STAGE(0, 3, 0);
    STAGE(1, 0, 1); STAGE(1, 1, 1);
    asm volatile("s_waitcnt vmcnt(4)" ::: "memory");   // own tile0 loads landed
    BAR();                                             // ...and everyone else's
    LDA(a0, 0, 0);

    int cur = 0;
    for (int t = 0; t < NT - 1; ++t) {
        const int nb = cur ^ 1;
        const int tA = (t + 2 < NT) ? t + 2 : NT - 1;  // clamped: dupes land dead
        // ph1: B[t] lower frags; issue B0[t+1]
        STAGE(t + 1, 2, nb);
        LDB(b0, 0, cur);
        BAR();
        MMA(a0, b0, 0, 0);
        BAR();
        // ph2: A[t] upper frags; issue B1[t+1]
        STAGE(t + 1, 3, nb);
        LDA(a1, 1, cur);
        BAR();
        MMA(a1, b0, 4, 0);
        BAR();
        // ph3: B[t] upper frags; issue A0[t+2]; publish A[t+1] (vmcnt 6)
        STAGE(tA, 0, cur);
        LDB(b1, 1, cur);
        BAR();
        MMA(a0, b1, 0, 2);
        asm volatile("s_waitcnt vmcnt(6)" ::: "memory");
        BAR();
        // ph4: A[t+1] lower frags from next buf; issue A1[t+2]; publish B[t+1]
        STAGE(tA, 1, cur);
        LDA(a0, 0, nb);
        BAR();
        MMA(a1, b1, 4, 2);
        asm volatile("s_waitcnt vmcnt(4)" ::: "memory");
        BAR();
        cur = nb;
    }
    // ---- epilogue: last tile, fully published by final ph3/ph4 waits ----
    LDB(b0, 0, cur);
    MMA(a0, b0, 0, 0);
    LDA(a1, 1, cur);
    MMA(a1, b0, 4, 0);
    LDB(b1, 1, cur);
    MMA(a0, b1, 0, 2);
    MMA(a1, b1, 4, 2);
    #undef BAR

    // ---- C write.  C/D layout: col = lane&15, row = (lane>>4)*4 + reg ----
    const int grow = bm * 256 + wm * 128 + hi * 4;
    const int gcol = bn * 256 + wn * 64 + lrow;
    if (MODE == 0) {
        float* C = (float*)Cout;
        #pragma unroll
        for (int m = 0; m < 8; ++m)
            #pragma unroll
            for (int n = 0; n < 4; ++n)
                #pragma unroll
                for (int r = 0; r < 4; ++r)
                    C[(long)(grow + m * 16 + r) * N + gcol + n * 16] = acc[m][n][r];
    } else if (MODE == 1) {
        unsigned short* C = (unsigned short*)Cout;
        #pragma unroll
        for (int m = 0; m < 8; ++m)
            #pragma unroll
            for (int n = 0; n < 4; ++n)
                #pragma unroll
                for (int r = 0; r < 4; ++r)
                    C[(long)(grow + m * 16 + r) * N + gcol + n * 16] = f2bf(acc[m][n][r]);
    } else {
        // fused SwiGLU: C holds h1 (bf16); acc = h3. write silu(h1)*h3 in place
        unsigned short* C = (unsigned short*)Cout;
        #pragma unroll
        for (int m = 0; m < 8; ++m)
            #pragma unroll
            for (int n = 0; n < 4; ++n)
                #pragma unroll
                for (int r = 0; r < 4; ++r) {
                    long idx = (long)(grow + m * 16 + r) * N + gcol + n * 16;
                    float h1v = bf2f(C[idx]);
                    float g = h1v / (1.0f + __expf(-h1v));
                    C[idx] = f2bf(g * acc[m][n][r]);
                }
    }
}

// ---- workspace layout (bytes) ----
//  [0)          W1 bf16 (90,177,536)
//  [90177536)   W3 bf16 (90,177,536)  -- later reused for W2
//  [180355072)  x  bf16 (33,554,432)
//  [213909504)  h1 bf16 (90,177,536)  -- fused swiglu written in-place by GEMM2
//  total 304,087,040
#define WS_NEEDED 304087040UL
#define DQBLK 512     // tail dequant blocks appended to GEMM1/GEMM2 dispatches

extern "C" void kernel_launch(void* const* d_in, const int* in_sizes, int n_in,
                              void* d_out, int out_size, void* d_ws, size_t ws_size,
                              hipStream_t stream) {
    const float* x   = (const float*)d_in[0];
    const int*   w1c = (const int*)d_in[1];
    const float* w1a = (const float*)d_in[2];
    const int*   w2c = (const int*)d_in[3];
    const float* w2a = (const float*)d_in[4];
    const int*   w3c = (const int*)d_in[5];
    const float* w3a = (const float*)d_in[6];

    if (ws_size < WS_NEEDED) return;   // fail loudly via validation

    char* ws = (char*)d_ws;
    unsigned short* W1 = (unsigned short*)(ws);
    unsigned short* W3 = (unsigned short*)(ws + 90177536);   // also W2 later
    unsigned short* Xb = (unsigned short*)(ws + 180355072);
    unsigned short* H1 = (unsigned short*)(ws + 213909504);

    // preamble: W1 dequant + x cast (one dispatch)
    pre_k<<<PREBLK, 256, 0, stream>>>(w1c, w1a, W1, x, Xb);

    const int g12 = (MTOK / 256) * (HID / 256);   // 688
    const int g3  = (MTOK / 256) * (DIM / 256);   // 256

    // h1 = x @ W1^T; tail blocks dequant W3 -> consumed by NEXT dispatch
    gemm256_k<1><<<g12 + DQBLK, 512, 0, stream>>>(Xb, W1, H1, MTOK, HID, DIM,
                                                  g12, w3c, w3a, W3);
    // h = silu(h1) * (x @ W3^T) in-place; tail blocks dequant W2 into W1's buf
    // (GEMM1 retired at dispatch boundary; this dispatch reads only Xb/W3/H1)
    gemm256_k<2><<<g12 + DQBLK, 512, 0, stream>>>(Xb, W3, H1, MTOK, HID, DIM,
                                                  g12, w2c, w2a, W1);
    // out = h @ W2^T (W2 lives in W1's buffer), fp32 output
    gemm256_k<0><<<g3, 512, 0, stream>>>(H1, W1, (float*)d_out, MTOK, DIM, HID,
                                         g3, nullptr, nullptr, nullptr);
}